// Round 20
// baseline (140.864 us; speedup 1.0000x reference)
//
#include <hip/hip_runtime.h>

// B=1024, S=256, D=128, H1=256, H2=64.
// h1_pre[s,h] = bias1[b,h] + sum_d keys[s,d] * Weff_b[d,h]   (K=128 GEMM)
//   Weff_b[d,h] = (W1b - W1c)[d,h] + q_b[d] * W1d[d,h]
//   bias1[b,h]  = b1[h] + q_b @ (W1a + W1c)
// R19 = R12's register structure with 64-row tiles (4 tiles, not 8):
//   halves block-wide barrier events (16 -> 8) and doubles phase length for
//   latency amortization. GEMM1 = two sequential 32-row m-chunks (acc[2][2],
//   bfrag[2][4] unchanged). GEMM2 per wave: M=32 (own s-half), N=16 o-slice,
//   K=256 (w2frag[8], acc2[2] unchanged). Staging 16 floats/thread (R7-proven).
//   LDS 69KB -> 2 blocks/CU at (512,4) — same residency as R12.

typedef unsigned short u16;
typedef unsigned int u32;
typedef short bf16x8 __attribute__((ext_vector_type(8)));
typedef float f32x4 __attribute__((ext_vector_type(4)));

#define NBATCH 1024
#define SLEN 256
#define DD 128
#define NH1 256
#define NH2 64

// ws layout (bytes)
#define WS_WBCT  0         // [256h][128k] bf16  (W1b - W1c)^T
#define WS_WDT   65536     // [256h][128k] bf16  W1d^T
#define WS_W2T   131072    // [64o][256h]  bf16  W2^T
#define WS_WDS   163840    // 65 f32 (Wd[64], bd)
#define WS_WSUM  165888    // [128d][256h] f32   W1a + W1c
#define WS_BIAS1 296960    // [1024][256] f32

// LDS map (main kernel)
#define L_KBUF   0         // [2][64][128] bf16, swzk (2 x 16KB; bases 16K-aligned)
#define L_H1     32768     // h1 bf16 [64 s][256 h] = [64][512B], swz (base 0x8000)
#define L_SCORES 65536     // f32[256]
#define L_BIAS   66560     // f32[256]
#define L_B2     67584     // f32[64]
#define L_WD     67840     // f32[66] (pad to 272)
#define L_WPART  68112     // f32[4][64]
#define L_RED4   69136     // f32[16]
#define L_SIZE   69200

__device__ __forceinline__ u16 f2bf_rne(float f){
  union { float f; unsigned u; } v; v.f = f;
  unsigned r = v.u + 0x7fffu + ((v.u >> 16) & 1u);
  return (u16)(r >> 16);
}
__device__ __forceinline__ u32 pack_trunc(float a, float b){
  return (__float_as_uint(a) >> 16) | (__float_as_uint(b) & 0xffff0000u);
}
__device__ __forceinline__ float b2fl(short s){
  return __uint_as_float(((u32)(u16)s) << 16);
}
__device__ __forceinline__ int swz(int byte){    // h1: 512B rows (key bits 9-11)
  return byte ^ (((byte >> 9) & 7) << 4);
}
__device__ __forceinline__ int swzk(int byte){   // kbuf: 256B rows (key bits 8-10)
  return byte ^ (((byte >> 8) & 7) << 4);
}
__device__ __forceinline__ float fsigmoid(float x){
  return __builtin_amdgcn_rcpf(1.f + __expf(-x));
}
__device__ __forceinline__ void barrier_lds(){
  asm volatile("s_waitcnt lgkmcnt(0)" ::: "memory");
  __builtin_amdgcn_s_barrier();
  __builtin_amdgcn_sched_barrier(0);
}

// ---- prep 1: fold weights to bf16, transposed; also Wsum = W1a + W1c ----
__global__ void prep_weights(const float* __restrict__ W1, const float* __restrict__ W2,
                             const float* __restrict__ Wd, const float* __restrict__ bd,
                             u16* __restrict__ WbcT, u16* __restrict__ WdT,
                             u16* __restrict__ W2T, float* __restrict__ WdS,
                             float* __restrict__ Wsum){
  int n = blockIdx.x;      // h (0..255)
  int k = threadIdx.x;     // 0..255
  if (k < DD){
    WbcT[n * DD + k] = f2bf_rne(W1[(128 + k) * NH1 + n] - W1[(256 + k) * NH1 + n]);
    WdT [n * DD + k] = f2bf_rne(W1[(384 + k) * NH1 + n]);
    Wsum[k * NH1 + n] = W1[k * NH1 + n] + W1[(256 + k) * NH1 + n];
  }
  if (n < NH2) W2T[n * 256 + k] = f2bf_rne(W2[k * NH2 + n]);
  if (n == 0 && k < NH2) WdS[k] = Wd[k];
  if (n == 0 && k == NH2) WdS[NH2] = bd[0];
}

// ---- prep 2: per-batch layer1 bias = b1 + q @ Wsum ----
__global__ void prep_bias(const float* __restrict__ q, const float* __restrict__ Wsum,
                          const float* __restrict__ b1, float* __restrict__ bias1){
  __shared__ float qsh[DD];
  int b = blockIdx.x, j = threadIdx.x;
  if (j < DD) qsh[j] = q[b * DD + j];
  __syncthreads();
  float acc = b1[j];
  #pragma unroll 8
  for (int d = 0; d < DD; ++d)
    acc += qsh[d] * Wsum[d * NH1 + j];
  bias1[b * NH1 + j] = acc;
}

// ---- main: one block per batch, 8 waves, 4 s-tiles of 64 rows ----
__global__ __launch_bounds__(512, 4)
void seqatt_main(const float* __restrict__ queries, const float* __restrict__ keys,
                 const int* __restrict__ keys_length,
                 const u16* __restrict__ WbcT, const u16* __restrict__ WdT,
                 const u16* __restrict__ W2Tg,
                 const float* __restrict__ WdS, const float* __restrict__ bias1g,
                 const float* __restrict__ b2g, float* __restrict__ out)
{
  __shared__ alignas(16) char smem[L_SIZE];
  float* scores = (float*)(smem + L_SCORES);
  float* bias1s = (float*)(smem + L_BIAS);
  float* b2s    = (float*)(smem + L_B2);
  float* wds    = (float*)(smem + L_WD);
  float* wpart  = (float*)(smem + L_WPART);
  float* red4   = (float*)(smem + L_RED4);

  const int b = blockIdx.x;
  const int tid = threadIdx.x;
  const int lane = tid & 63;
  const int wave = tid >> 6;          // 0..7
  const int l15 = lane & 15;
  const int g   = lane >> 4;          // 0..3
  const int r = tid >> 3, seg = tid & 7;   // staging: 8 threads/row, 16 floats each

  if (tid < 256) bias1s[tid] = bias1g[b * NH1 + tid];
  if (tid < 64) b2s[tid] = b2g[tid];
  if (tid < 65) wds[tid] = WdS[tid];
  const int klen = keys_length[b];
  const float* kbb = keys + (long)b * SLEN * DD;

  // staging registers (16 floats/thread/tile)
  float4 k0, k1, k2, k3;
#define ISSUE(t) do { const float* p_ = kbb + (((t) << 6) + r) * DD + (seg << 4); \
    k0 = *(const float4*)p_;       k1 = *(const float4*)(p_ + 4); \
    k2 = *(const float4*)(p_ + 8); k3 = *(const float4*)(p_ + 12); } while (0)
#define STORE(t) do { int bb_ = (((t) & 1) << 14) + (r << 8) + (seg << 5); \
    uint4 w_; \
    w_.x = pack_trunc(k0.x, k0.y); w_.y = pack_trunc(k0.z, k0.w); \
    w_.z = pack_trunc(k1.x, k1.y); w_.w = pack_trunc(k1.z, k1.w); \
    *(uint4*)(smem + swzk(bb_)) = w_; \
    w_.x = pack_trunc(k2.x, k2.y); w_.y = pack_trunc(k2.z, k2.w); \
    w_.z = pack_trunc(k3.x, k3.y); w_.w = pack_trunc(k3.z, k3.w); \
    *(uint4*)(smem + swzk(bb_ + 16)) = w_; } while (0)

  ISSUE(0);

  // Weff fragments (GEMM1 A-operand), h-slice = wave*32..+32: 32 VGPRs
  bf16x8 bfrag[2][4];
  {
    const float* qb = queries + b * DD;
    #pragma unroll
    for (int nt = 0; nt < 2; ++nt){
      int n = (wave << 5) + (nt << 4) + l15;
      #pragma unroll
      for (int kk = 0; kk < 4; ++kk){
        int k0i = (g << 3) + (kk << 5);
        bf16x8 bc = *(const bf16x8*)(WbcT + n * DD + k0i);
        bf16x8 wd = *(const bf16x8*)(WdT  + n * DD + k0i);
        float4 q0 = *(const float4*)(qb + k0i);
        float4 q1 = *(const float4*)(qb + k0i + 4);
        float qa[8] = {q0.x, q0.y, q0.z, q0.w, q1.x, q1.y, q1.z, q1.w};
        union { u16 s[8]; bf16x8 v; } o;
        #pragma unroll
        for (int j = 0; j < 8; ++j)
          o.s[j] = f2bf_rne(fmaf(qa[j], b2fl(wd[j]), b2fl(bc[j])));
        bfrag[nt][kk] = o.v;
      }
    }
  }
  // GEMM2 split: wave = (s-half shh)*4 + o-slice; M=32, N=16, K=256: w2frag 32 VGPRs
  const int shh = wave >> 2;          // 0..1: s-rows shh*32..+32
  const int ob = (wave & 3) << 4;     // o-slice base
  bf16x8 w2frag[8];
  #pragma unroll
  for (int kk = 0; kk < 8; ++kk)
    w2frag[kk] = *(const bf16x8*)(W2Tg + (ob + l15) * 256 + (kk << 5) + (g << 3));

  STORE(0);
  barrier_lds();   // kbuf[0], scalars visible

  const f32x4 fz = {0.f, 0.f, 0.f, 0.f};

  for (int st = 0; st < 4; ++st){
    const int s0 = st << 6;
    const int kb_base = (st & 1) << 14;

    if (st < 3) ISSUE(st + 1);   // global->reg, flies under GEMM1+GEMM2

    // ---- GEMM1 (swapped), two 32-row m-chunks: s = mc*32+mt*16+l15, h = wave*32+nt*16+g*4+i ----
    #pragma unroll
    for (int mc = 0; mc < 2; ++mc){
      f32x4 acc[2][2];
      #pragma unroll
      for (int mt = 0; mt < 2; ++mt)
        #pragma unroll
        for (int nt = 0; nt < 2; ++nt) acc[mt][nt] = fz;
      #pragma unroll
      for (int kk = 0; kk < 4; ++kk){
        bf16x8 af[2];
        #pragma unroll
        for (int mt = 0; mt < 2; ++mt)
          af[mt] = *(const bf16x8*)(smem + swzk(kb_base + (((mc << 5) + (mt << 4) + l15) << 8) + (kk << 6) + (g << 4)));
        #pragma unroll
        for (int mt = 0; mt < 2; ++mt)
          #pragma unroll
          for (int nt = 0; nt < 2; ++nt)
            acc[mt][nt] = __builtin_amdgcn_mfma_f32_16x16x32_bf16(bfrag[nt][kk], af[mt], acc[mt][nt], 0, 0, 0);
      }
      // bias + sigmoid -> h1 LDS bf16, vector 8B writes (own h-columns)
      #pragma unroll
      for (int nt = 0; nt < 2; ++nt){
        float4 bia = *(const float4*)(bias1s + (wave << 5) + (nt << 4) + (g << 2));
        #pragma unroll
        for (int mt = 0; mt < 2; ++mt){
          float v0 = fsigmoid(acc[mt][nt][0] + bia.x);
          float v1 = fsigmoid(acc[mt][nt][1] + bia.y);
          float v2 = fsigmoid(acc[mt][nt][2] + bia.z);
          float v3 = fsigmoid(acc[mt][nt][3] + bia.w);
          uint2 p; p.x = pack_trunc(v0, v1); p.y = pack_trunc(v2, v3);
          int s = (mc << 5) + (mt << 4) + l15;
          int hb = (wave << 5) + (nt << 4) + (g << 2);
          *(uint2*)(smem + swz(L_H1 + (s << 9) + (hb << 1))) = p;
        }
      }
    }
    barrier_lds();   // (E) h1 (all 64 rows) visible to all waves

    // ---- GEMM2 (swapped): rows s = shh*32+mt*16+l15, o-slice ob..+16, K=256 ----
    f32x4 acc2[2];
    acc2[0] = fz; acc2[1] = fz;
    #pragma unroll
    for (int kk = 0; kk < 8; ++kk){
      bf16x8 a2[2];
      #pragma unroll
      for (int mt = 0; mt < 2; ++mt)
        a2[mt] = *(const bf16x8*)(smem + swz(L_H1 + (((shh << 5) + (mt << 4) + l15) << 9) + (kk << 6) + (g << 4)));
      #pragma unroll
      for (int mt = 0; mt < 2; ++mt)
        acc2[mt] = __builtin_amdgcn_mfma_f32_16x16x32_bf16(w2frag[kk], a2[mt], acc2[mt], 0, 0, 0);
    }

    // ---- sigmoid + Wd dot + reduce over g -> wpart[o-slice][s] ----
    {
      float pp0 = 0.f, pp1 = 0.f;
      #pragma unroll
      for (int i = 0; i < 4; ++i){
        int o = ob + (g << 2) + i;
        float b2v = b2s[o], wdv = wds[o];
        pp0 += fsigmoid(acc2[0][i] + b2v) * wdv;
        pp1 += fsigmoid(acc2[1][i] + b2v) * wdv;
      }
      pp0 += __shfl_xor(pp0, 16); pp0 += __shfl_xor(pp0, 32);
      pp1 += __shfl_xor(pp1, 16); pp1 += __shfl_xor(pp1, 32);
      if (lane < 16){
        wpart[((wave & 3) << 6) + (shh << 5) + l15]      = pp0;
        wpart[((wave & 3) << 6) + (shh << 5) + 16 + l15] = pp1;
      }
    }

    if (st < 3) STORE(st + 1);   // write-late into other kbuf

    barrier_lds();   // (G) wpart + next kbuf visible; h1/kbuf reads done

    // ---- finalize scores for this tile (64 rows) ----
    if (tid < 64){
      float v = wpart[tid] + wpart[64 + tid] + wpart[128 + tid] + wpart[192 + tid];
      int s = s0 + tid;
      scores[s] = (s < klen) ? (v + wds[64]) * 0.08838834764831845f : -1e30f;
    }
    // next (E) barrier orders: this tile's wpart reads before next writes
  }

  barrier_lds();   // scores visible

  // ---- softmax over S=256 (8 waves; upper half contributes -inf/0) ----
  {
    float v = (tid < 256) ? scores[tid] : -1e30f;
    float m = v;
    #pragma unroll
    for (int off = 32; off >= 1; off >>= 1) m = fmaxf(m, __shfl_xor(m, off));
    if (lane == 0) red4[wave] = m;
    __syncthreads();
    float mx = red4[0];
    #pragma unroll
    for (int w = 1; w < 8; ++w) mx = fmaxf(mx, red4[w]);
    float e = (tid < 256) ? __expf(v - mx) : 0.f;
    float ssum = e;
    #pragma unroll
    for (int off = 32; off >= 1; off >>= 1) ssum += __shfl_xor(ssum, off);
    if (lane == 0) red4[8 + wave] = ssum;
    __syncthreads();
    float tot = 0.f;
    #pragma unroll
    for (int w = 0; w < 8; ++w) tot += red4[8 + w];
    if (tid < 256) scores[tid] = e * __builtin_amdgcn_rcpf(tot);
    __syncthreads();
  }

  // ---- out[b][d] = sum_s w[s] * keys[b][s][d] (fp32; keys L2/L3-resident) ----
  {
    float* red = (float*)smem;   // kbuf area, free now
    int d = tid & 127, q4 = tid >> 7;   // 4 quarters of 64 s each
    const float* kb = keys + ((long)b * SLEN + q4 * 64) * DD + d;
    const float* sc = scores + q4 * 64;
    float acc = 0.f;
    #pragma unroll 4
    for (int s2 = 0; s2 < 64; ++s2) acc += sc[s2] * kb[s2 * DD];
    red[tid] = acc;
    __syncthreads();
    if (tid < 128)
      out[b * DD + tid] = (red[tid] + red[128 + tid]) + (red[256 + tid] + red[384 + tid]);
  }
#undef ISSUE
#undef STORE
}

extern "C" void kernel_launch(void* const* d_in, const int* in_sizes, int n_in,
                              void* d_out, int out_size, void* d_ws, size_t ws_size,
                              hipStream_t stream) {
  const float* queries     = (const float*)d_in[0];
  const float* keys        = (const float*)d_in[1];
  const int*   keys_length = (const int*)d_in[2];
  const float* W1 = (const float*)d_in[3];
  const float* b1 = (const float*)d_in[4];
  const float* W2 = (const float*)d_in[5];
  const float* b2 = (const float*)d_in[6];
  const float* Wd = (const float*)d_in[7];
  const float* bd = (const float*)d_in[8];
  float* out = (float*)d_out;
  char* ws = (char*)d_ws;

  u16*   WbcT  = (u16*)(ws + WS_WBCT);
  u16*   WdT   = (u16*)(ws + WS_WDT);
  u16*   W2T   = (u16*)(ws + WS_W2T);
  float* WdS   = (float*)(ws + WS_WDS);
  float* Wsum  = (float*)(ws + WS_WSUM);
  float* bias1 = (float*)(ws + WS_BIAS1);

  prep_weights<<<dim3(256), dim3(256), 0, stream>>>(W1, W2, Wd, bd, WbcT, WdT, W2T, WdS, Wsum);
  prep_bias<<<dim3(NBATCH), dim3(256), 0, stream>>>(queries, Wsum, b1, bias1);
  seqatt_main<<<dim3(NBATCH), dim3(512), 0, stream>>>(queries, keys, keys_length,
                                                      WbcT, WdT, W2T, WdS, bias1, b2, out);
}

// Round 21
// 89.511 us; speedup vs baseline: 1.5737x; 1.5737x over previous
//
#include <hip/hip_runtime.h>

// B=1024, S=256, D=128, H1=256, H2=64.
// h1_pre[s,h] = bias1[b,h] + sum_d keys[s,d] * Weff_b[d,h]   (K=128 GEMM)
//   Weff_b[d,h] = (W1b - W1c)[d,h] + q_b[d] * W1d[d,h]
//   bias1[b,h]  = b1[h] + q_b @ (W1a + W1c)
// FINAL = R12 (session best, 89.6us): 8 thin waves (512 thr), per-wave h-slice 32
//   (bfrag 32 VGPR), GEMM2 = (s-half, o-16) per wave full-K (w2frag 32, acc2 8),
//   reg-staged bf16 keys double-buffered (issue-early/write-late), 2 barriers/tile,
//   __launch_bounds__(512,4): 4 waves/EU resident (~40% occ), no spills.
// Session findings: (a) resident waves/EU == launch_bounds 2nd arg on this
//   toolchain; register budget = 512/arg UNIFIED (arch+AGPR) — exceeding it
//   spills catastrophically (R3/R5/R8/R13/R15/R19). (b) At this budget only
//   this lean body fits; occupancy/ILP/barrier/tile variations are all flat
//   or worse. Wall ~= sum of phase latencies; all pipes <=31%.

typedef unsigned short u16;
typedef unsigned int u32;
typedef short bf16x8 __attribute__((ext_vector_type(8)));
typedef float f32x4 __attribute__((ext_vector_type(4)));

#define NBATCH 1024
#define SLEN 256
#define DD 128
#define NH1 256
#define NH2 64

// ws layout (bytes)
#define WS_WBCT  0         // [256h][128k] bf16  (W1b - W1c)^T
#define WS_WDT   65536     // [256h][128k] bf16  W1d^T
#define WS_W2T   131072    // [64o][256h]  bf16  W2^T
#define WS_WDS   163840    // 65 f32 (Wd[64], bd)
#define WS_WSUM  165888    // [128d][256h] f32   W1a + W1c
#define WS_BIAS1 296960    // [1024][256] f32

// LDS map (main kernel)
#define L_KBUF   0         // [2][32][128] bf16, swzk (2 x 8KB)
#define L_H1     16384     // h1 bf16 [32 s][256 h] = [32][512B], swz
#define L_SCORES 32768     // f32[256]
#define L_BIAS   33792     // f32[256]
#define L_B2     34816     // f32[64]
#define L_WD     35072     // f32[66] (pad)
#define L_WPART  35344     // f32[4][32]
#define L_RED4   35856     // f32[16]
#define L_SIZE   35920

__device__ __forceinline__ u16 f2bf_rne(float f){
  union { float f; unsigned u; } v; v.f = f;
  unsigned r = v.u + 0x7fffu + ((v.u >> 16) & 1u);
  return (u16)(r >> 16);
}
__device__ __forceinline__ u32 pack_trunc(float a, float b){
  return (__float_as_uint(a) >> 16) | (__float_as_uint(b) & 0xffff0000u);
}
__device__ __forceinline__ float b2fl(short s){
  return __uint_as_float(((u32)(u16)s) << 16);
}
__device__ __forceinline__ int swz(int byte){    // h1: 512B rows
  return byte ^ (((byte >> 9) & 7) << 4);
}
__device__ __forceinline__ int swzk(int byte){   // kbuf: 256B rows
  return byte ^ (((byte >> 8) & 7) << 4);
}
__device__ __forceinline__ float fsigmoid(float x){
  return __builtin_amdgcn_rcpf(1.f + __expf(-x));
}
__device__ __forceinline__ void barrier_lds(){
  asm volatile("s_waitcnt lgkmcnt(0)" ::: "memory");
  __builtin_amdgcn_s_barrier();
  __builtin_amdgcn_sched_barrier(0);
}

// ---- prep 1: fold weights to bf16, transposed; also Wsum = W1a + W1c ----
__global__ void prep_weights(const float* __restrict__ W1, const float* __restrict__ W2,
                             const float* __restrict__ Wd, const float* __restrict__ bd,
                             u16* __restrict__ WbcT, u16* __restrict__ WdT,
                             u16* __restrict__ W2T, float* __restrict__ WdS,
                             float* __restrict__ Wsum){
  int n = blockIdx.x;      // h (0..255)
  int k = threadIdx.x;     // 0..255
  if (k < DD){
    WbcT[n * DD + k] = f2bf_rne(W1[(128 + k) * NH1 + n] - W1[(256 + k) * NH1 + n]);
    WdT [n * DD + k] = f2bf_rne(W1[(384 + k) * NH1 + n]);
    Wsum[k * NH1 + n] = W1[k * NH1 + n] + W1[(256 + k) * NH1 + n];
  }
  if (n < NH2) W2T[n * 256 + k] = f2bf_rne(W2[k * NH2 + n]);
  if (n == 0 && k < NH2) WdS[k] = Wd[k];
  if (n == 0 && k == NH2) WdS[NH2] = bd[0];
}

// ---- prep 2: per-batch layer1 bias = b1 + q @ Wsum ----
__global__ void prep_bias(const float* __restrict__ q, const float* __restrict__ Wsum,
                          const float* __restrict__ b1, float* __restrict__ bias1){
  __shared__ float qsh[DD];
  int b = blockIdx.x, j = threadIdx.x;
  if (j < DD) qsh[j] = q[b * DD + j];
  __syncthreads();
  float acc = b1[j];
  #pragma unroll 8
  for (int d = 0; d < DD; ++d)
    acc += qsh[d] * Wsum[d * NH1 + j];
  bias1[b * NH1 + j] = acc;
}

// ---- main: one block per batch, 8 waves, 8 s-tiles of 32 rows ----
__global__ __launch_bounds__(512, 4)
void seqatt_main(const float* __restrict__ queries, const float* __restrict__ keys,
                 const int* __restrict__ keys_length,
                 const u16* __restrict__ WbcT, const u16* __restrict__ WdT,
                 const u16* __restrict__ W2Tg,
                 const float* __restrict__ WdS, const float* __restrict__ bias1g,
                 const float* __restrict__ b2g, float* __restrict__ out)
{
  __shared__ alignas(16) char smem[L_SIZE];
  float* scores = (float*)(smem + L_SCORES);
  float* bias1s = (float*)(smem + L_BIAS);
  float* b2s    = (float*)(smem + L_B2);
  float* wds    = (float*)(smem + L_WD);
  float* wpart  = (float*)(smem + L_WPART);
  float* red4   = (float*)(smem + L_RED4);

  const int b = blockIdx.x;
  const int tid = threadIdx.x;
  const int lane = tid & 63;
  const int wave = tid >> 6;          // 0..7
  const int l15 = lane & 15;
  const int g   = lane >> 4;          // 0..3
  const int r = tid >> 4, seg = tid & 15;  // staging: 16 threads/row, 8 floats each

  if (tid < 256) bias1s[tid] = bias1g[b * NH1 + tid];
  if (tid < 64) b2s[tid] = b2g[tid];
  if (tid < 65) wds[tid] = WdS[tid];
  const int klen = keys_length[b];
  const float* kbb = keys + (long)b * SLEN * DD;

  // staging registers (8 floats/thread/tile)
  float4 k0, k1;
#define ISSUE(t) do { const float* p_ = kbb + (((t) << 5) + r) * DD + (seg << 3); \
    k0 = *(const float4*)p_; k1 = *(const float4*)(p_ + 4); } while (0)
#define STORE(t) do { int bb_ = (((t) & 1) << 13) + (r << 8) + (seg << 4); \
    uint4 w_; \
    w_.x = pack_trunc(k0.x, k0.y); w_.y = pack_trunc(k0.z, k0.w); \
    w_.z = pack_trunc(k1.x, k1.y); w_.w = pack_trunc(k1.z, k1.w); \
    *(uint4*)(smem + swzk(bb_)) = w_; } while (0)

  ISSUE(0);

  // Weff fragments (GEMM1 A-operand), h-slice = wave*32..+32: 32 VGPRs
  bf16x8 bfrag[2][4];
  {
    const float* qb = queries + b * DD;
    #pragma unroll
    for (int nt = 0; nt < 2; ++nt){
      int n = (wave << 5) + (nt << 4) + l15;
      #pragma unroll
      for (int kk = 0; kk < 4; ++kk){
        int k0i = (g << 3) + (kk << 5);
        bf16x8 bc = *(const bf16x8*)(WbcT + n * DD + k0i);
        bf16x8 wd = *(const bf16x8*)(WdT  + n * DD + k0i);
        float4 q0 = *(const float4*)(qb + k0i);
        float4 q1 = *(const float4*)(qb + k0i + 4);
        float qa[8] = {q0.x, q0.y, q0.z, q0.w, q1.x, q1.y, q1.z, q1.w};
        union { u16 s[8]; bf16x8 v; } o;
        #pragma unroll
        for (int j = 0; j < 8; ++j)
          o.s[j] = f2bf_rne(fmaf(qa[j], b2fl(wd[j]), b2fl(bc[j])));
        bfrag[nt][kk] = o.v;
      }
    }
  }
  // GEMM2 split: wave = (s-half sh) * 4 + o-slice; full K=256: w2frag 32 VGPRs
  const int sh = wave >> 2;           // 0..1: s-rows sh*16..+16
  const int ob = (wave & 3) << 4;     // o-slice base
  bf16x8 w2frag[8];
  #pragma unroll
  for (int kk = 0; kk < 8; ++kk)
    w2frag[kk] = *(const bf16x8*)(W2Tg + (ob + l15) * 256 + (kk << 5) + (g << 3));

  STORE(0);
  barrier_lds();   // kbuf[0], scalars visible

  const f32x4 fz = {0.f, 0.f, 0.f, 0.f};

  for (int st = 0; st < 8; ++st){
    const int s0 = st << 5;
    const int kb_base = (st & 1) << 13;

    if (st < 7) ISSUE(st + 1);   // global->reg, flies under GEMM1+GEMM2

    // ---- GEMM1 (swapped): lane holds h1^T: s = mt*16+l15, h = wave*32+nt*16+g*4+i ----
    f32x4 acc[2][2];
    #pragma unroll
    for (int mt = 0; mt < 2; ++mt)
      #pragma unroll
      for (int nt = 0; nt < 2; ++nt) acc[mt][nt] = fz;
    #pragma unroll
    for (int kk = 0; kk < 4; ++kk){
      bf16x8 af[2];
      #pragma unroll
      for (int mt = 0; mt < 2; ++mt)
        af[mt] = *(const bf16x8*)(smem + swzk(kb_base + (((mt << 4) + l15) << 8) + (kk << 6) + (g << 4)));
      #pragma unroll
      for (int mt = 0; mt < 2; ++mt)
        #pragma unroll
        for (int nt = 0; nt < 2; ++nt)
          acc[mt][nt] = __builtin_amdgcn_mfma_f32_16x16x32_bf16(bfrag[nt][kk], af[mt], acc[mt][nt], 0, 0, 0);
    }

    // ---- bias + sigmoid -> h1 LDS bf16, vector 8B writes (own h-columns) ----
    #pragma unroll
    for (int nt = 0; nt < 2; ++nt){
      float4 bia = *(const float4*)(bias1s + (wave << 5) + (nt << 4) + (g << 2));
      #pragma unroll
      for (int mt = 0; mt < 2; ++mt){
        float v0 = fsigmoid(acc[mt][nt][0] + bia.x);
        float v1 = fsigmoid(acc[mt][nt][1] + bia.y);
        float v2 = fsigmoid(acc[mt][nt][2] + bia.z);
        float v3 = fsigmoid(acc[mt][nt][3] + bia.w);
        uint2 p; p.x = pack_trunc(v0, v1); p.y = pack_trunc(v2, v3);
        int s = (mt << 4) + l15;
        int hb = (wave << 5) + (nt << 4) + (g << 2);
        *(uint2*)(smem + swz(L_H1 + (s << 9) + (hb << 1))) = p;
      }
    }
    barrier_lds();   // (E) h1 visible to all waves

    // ---- GEMM2 (swapped): rows s = sh*16+l15, o-slice ob..+16, full K=256 ----
    f32x4 acc2 = fz;
    #pragma unroll
    for (int kk = 0; kk < 8; ++kk){
      bf16x8 a2 = *(const bf16x8*)(smem + swz(L_H1 + (((sh << 4) + l15) << 9) + (kk << 6) + (g << 4)));
      acc2 = __builtin_amdgcn_mfma_f32_16x16x32_bf16(w2frag[kk], a2, acc2, 0, 0, 0);
    }

    // ---- sigmoid + Wd dot + reduce over g -> wpart[o-slice][s] ----
    {
      float pp = 0.f;
      #pragma unroll
      for (int i = 0; i < 4; ++i){
        int o = ob + (g << 2) + i;
        pp += fsigmoid(acc2[i] + b2s[o]) * wds[o];
      }
      pp += __shfl_xor(pp, 16); pp += __shfl_xor(pp, 32);
      if (lane < 16)
        wpart[((wave & 3) << 5) + (sh << 4) + l15] = pp;
    }

    if (st < 7) STORE(st + 1);   // write-late into other kbuf

    barrier_lds();   // (G) wpart + next kbuf visible; h1 reads done

    // ---- finalize scores for this tile ----
    if (tid < 32){
      float v = wpart[tid] + wpart[32 + tid] + wpart[64 + tid] + wpart[96 + tid];
      int s = s0 + tid;
      scores[s] = (s < klen) ? (v + wds[64]) * 0.08838834764831845f : -1e30f;
    }
    // next (E) barrier orders: this tile's wpart reads before next writes
  }

  barrier_lds();   // scores visible

  // ---- softmax over S=256 (8 waves; upper half contributes -inf/0) ----
  {
    float v = (tid < 256) ? scores[tid] : -1e30f;
    float m = v;
    #pragma unroll
    for (int off = 32; off >= 1; off >>= 1) m = fmaxf(m, __shfl_xor(m, off));
    if (lane == 0) red4[wave] = m;
    __syncthreads();
    float mx = red4[0];
    #pragma unroll
    for (int w = 1; w < 8; ++w) mx = fmaxf(mx, red4[w]);
    float e = (tid < 256) ? __expf(v - mx) : 0.f;
    float ssum = e;
    #pragma unroll
    for (int off = 32; off >= 1; off >>= 1) ssum += __shfl_xor(ssum, off);
    if (lane == 0) red4[8 + wave] = ssum;
    __syncthreads();
    float tot = 0.f;
    #pragma unroll
    for (int w = 0; w < 8; ++w) tot += red4[8 + w];
    if (tid < 256) scores[tid] = e * __builtin_amdgcn_rcpf(tot);
    __syncthreads();
  }

  // ---- out[b][d] = sum_s w[s] * keys[b][s][d] (fp32; keys L3-resident) ----
  {
    float* red = (float*)smem;   // kbuf area, free now
    int d = tid & 127, q4 = tid >> 7;   // 4 quarters of 64 s each
    const float* kb = keys + ((long)b * SLEN + q4 * 64) * DD + d;
    const float* sc = scores + q4 * 64;
    float acc = 0.f;
    #pragma unroll 4
    for (int s2 = 0; s2 < 64; ++s2) acc += sc[s2] * kb[s2 * DD];
    red[tid] = acc;
    __syncthreads();
    if (tid < 128)
      out[b * DD + tid] = (red[tid] + red[128 + tid]) + (red[256 + tid] + red[384 + tid]);
  }
#undef ISSUE
#undef STORE
}

extern "C" void kernel_launch(void* const* d_in, const int* in_sizes, int n_in,
                              void* d_out, int out_size, void* d_ws, size_t ws_size,
                              hipStream_t stream) {
  const float* queries     = (const float*)d_in[0];
  const float* keys        = (const float*)d_in[1];
  const int*   keys_length = (const int*)d_in[2];
  const float* W1 = (const float*)d_in[3];
  const float* b1 = (const float*)d_in[4];
  const float* W2 = (const float*)d_in[5];
  const float* b2 = (const float*)d_in[6];
  const float* Wd = (const float*)d_in[7];
  const float* bd = (const float*)d_in[8];
  float* out = (float*)d_out;
  char* ws = (char*)d_ws;

  u16*   WbcT  = (u16*)(ws + WS_WBCT);
  u16*   WdT   = (u16*)(ws + WS_WDT);
  u16*   W2T   = (u16*)(ws + WS_W2T);
  float* WdS   = (float*)(ws + WS_WDS);
  float* Wsum  = (float*)(ws + WS_WSUM);
  float* bias1 = (float*)(ws + WS_BIAS1);

  prep_weights<<<dim3(256), dim3(256), 0, stream>>>(W1, W2, Wd, bd, WbcT, WdT, W2T, WdS, Wsum);
  prep_bias<<<dim3(NBATCH), dim3(256), 0, stream>>>(queries, Wsum, b1, bias1);
  seqatt_main<<<dim3(NBATCH), dim3(512), 0, stream>>>(queries, keys, keys_length,
                                                      WbcT, WdT, W2T, WdS, bias1, b2, out);
}